// Round 5
// baseline (262.074 us; speedup 1.0000x reference)
//
#include <hip/hip_runtime.h>
#include <math.h>

constexpr int kH = 64, kW = 128, kB = 2, kS = 4;
constexpr int kNP = kH * kW;          // 8192 points per set
constexpr int kPairs = kB * kS;       // 8
constexpr int kDirs = kPairs * 2;     // 16
constexpr float kPen = 32768.0f;      // exclusion penalty (bf16-exact pow2)
constexpr float kPi = 3.14159265358979323846f;
constexpr float kFovUp = 3.0f * kPi / 180.0f;
constexpr float kFovDown = -25.0f * kPi / 180.0f;

typedef short short8 __attribute__((ext_vector_type(8)));
typedef unsigned short ushort8 __attribute__((ext_vector_type(8)));
typedef float floatx4 __attribute__((ext_vector_type(4)));

// nn tiling: block=256 (4 waves); per wave 16 query tiles of 16 = 256 queries
// -> 1024 queries/block. Candidates: CCH per chunk staged in LDS (32 KB).
constexpr int NCC = 8;                // candidate chunks
constexpr int CCH = kNP / NCC;        // 1024
constexpr int NQB = 8;                // query blocks (8192/1024)
// grid = 16 * 8 * 8 = 1024 blocks = 4/CU

// ws layout (float offsets)
// cf   : [kDirs][kNP][16] bf16 (ushort) -> 1048576 floats @ 0       (4 MB)
// pts  : [kDirs][kNP] float4 (query-role) -> 524288 @ 1048576       (2 MB)
// min  : [kDirs][kNP] u32 -> 131072 @ 1572864                       (0.5 MB)
// mval : [kDirs] f32 -> 16 @ 1703936
constexpr size_t OFF_PTS = 1048576;
constexpr size_t OFF_MIN = 1572864;
constexpr size_t OFF_MVAL = 1703936;

__device__ __forceinline__ unsigned short f2bf(float v) {
  unsigned u = __float_as_uint(v);
  unsigned r = u + 0x7FFFu + ((u >> 16) & 1u);   // RNE
  return (unsigned short)(r >> 16);
}
__device__ __forceinline__ float bf2f(unsigned short b) {
  return __uint_as_float(((unsigned)b) << 16);
}

// Candidate record, 16 bf16 slots. F-slots pair with query G-slots:
//  k : 0    1    2    3    4    5    6    7  | 8    9    10   11   12-15
//  F : Xh   Xl   Xh   Yh   Yl   Yh   Zh   Zl | Zh   Ch   Cl   Cl2  0
//  G : xh   xh   xl   yh   yh   yl   zh   zh | zl   1    1    1    0
// sum_k F*G = X*x + Y*y + Z*z + ct  (dropping only lo*lo terms ~2e-4)
__device__ __forceinline__ void write_rec(unsigned short* dst, float X, float Y,
                                          float Z, float ct) {
  unsigned short Xh = f2bf(X), Yh = f2bf(Y), Zh = f2bf(Z);
  unsigned short Xl = f2bf(X - bf2f(Xh));
  unsigned short Yl = f2bf(Y - bf2f(Yh));
  unsigned short Zl = f2bf(Z - bf2f(Zh));
  unsigned short Ch = f2bf(ct);
  float c1 = ct - bf2f(Ch);
  unsigned short Cl = f2bf(c1);
  unsigned short Cl2 = f2bf(c1 - bf2f(Cl));
  ushort8 lo8 = {Xh, Xl, Xh, Yh, Yl, Yh, Zh, Zl};
  ushort8 hi8 = {Zh, Ch, Cl, Cl2, 0, 0, 0, 0};
  *(ushort8*)dst = lo8;
  *(ushort8*)(dst + 8) = hi8;
}

__global__ __launch_bounds__(256) void prep_kernel(
    const float* __restrict__ rv, const float* __restrict__ tgt,
    unsigned short* __restrict__ cf, float4* __restrict__ pts,
    unsigned* __restrict__ minarr) {
  int idx = blockIdx.x * 256 + threadIdx.x;   // [0, kPairs*kNP)
  int p = idx >> 13;
  int k = idx & (kNP - 1);
  int h = k >> 7;
  int w = k & 127;

  float r = rv[idx];
  float pitch = (1.0f - (h + 0.5f) * (1.0f / kH)) * (kFovUp - kFovDown) + kFovDown;
  float yaw = -(((w + 0.5f) * (1.0f / kW)) * 2.0f - 1.0f) * kPi;
  float cp = cosf(pitch), sp = sinf(pitch);
  float cy = cosf(yaw), sy = sinf(yaw);
  float px = r * cp * cy, py = r * cp * sy, pz = r * sp;
  float mo = (r > 0.0f) ? 1.0f : 0.0f;

  const float* tb = tgt + (size_t)p * 4 * kNP;
  float mt = (tb[k] > 0.0f) ? 1.0f : 0.0f;
  float tx = tb[kNP + k], ty = tb[2 * kNP + k], tz = tb[3 * kNP + k];

  float no = px * px + py * py + pz * pz;
  float nt = tx * tx + ty * ty + tz * tz;
  float co = no + kPen * (1.0f - mo);   // candidate-const for rv points
  float ct = nt + kPen * (1.0f - mt);   // candidate-const for tgt points

  int d0 = 2 * p, d1 = d0 + 1;
  // dir d0: queries = rv points, candidates = tgt points
  pts[(size_t)d0 * kNP + k] = make_float4(px, py, pz, co);  // .w>=kPen/2 => invalid query
  pts[(size_t)d1 * kNP + k] = make_float4(tx, ty, tz, ct);
  write_rec(cf + ((size_t)d0 * kNP + k) * 16, -2.0f * tx, -2.0f * ty, -2.0f * tz, ct);
  write_rec(cf + ((size_t)d1 * kNP + k) * 16, -2.0f * px, -2.0f * py, -2.0f * pz, co);

  minarr[(size_t)d0 * kNP + k] = 0xFFFFFFFFu;
  minarr[(size_t)d1 * kNP + k] = 0xFFFFFFFFu;
}

__global__ __launch_bounds__(256, 4) void nn_kernel(
    const unsigned short* __restrict__ cf, const float4* __restrict__ pts,
    unsigned* __restrict__ minarr) {
  __shared__ unsigned short sc[CCH * 16];   // 32 KB candidate records

  int bid = blockIdx.x;
  int d = bid >> 6;            // 64 blocks per dir
  int qb = (bid >> 3) & 7;
  int ch = bid & 7;
  int t = threadIdx.x;

  const float4* src = (const float4*)(cf + ((size_t)d * kNP + ch * CCH) * 16);
  float4* dst = (float4*)sc;
#pragma unroll
  for (int i = 0; i < 8; ++i) dst[t + i * 256] = src[t + i * 256];
  __syncthreads();

  int wave = t >> 6, lane = t & 63;
  int n = lane & 15, q = lane >> 4;          // quad = k-group (verified layout)
  int qbase = d * kNP + qb * 1024 + wave * 256;

  const short one_bf = (short)0x3F80;        // bf16(1.0)
  short8 bfr[16];
  float mn[16];
#pragma unroll
  for (int i = 0; i < 16; ++i) {
    short8 b = (short8){0, 0, 0, 0, 0, 0, 0, 0};
    if (q < 2) {
      float4 P = pts[qbase + i * 16 + n];
      unsigned short xh = f2bf(P.x), yh = f2bf(P.y), zh = f2bf(P.z);
      unsigned short xl = f2bf(P.x - bf2f(xh));
      unsigned short yl = f2bf(P.y - bf2f(yh));
      unsigned short zl = f2bf(P.z - bf2f(zh));
      if (q == 0)
        b = (short8){(short)xh, (short)xh, (short)xl, (short)yh,
                     (short)yh, (short)yl, (short)zh, (short)zh};
      else
        b = (short8){(short)zl, one_bf, one_bf, one_bf, 0, 0, 0, 0};
    }
    bfr[i] = b;
    mn[i] = 3.0e38f;
  }

  floatx4 zf = {0.0f, 0.0f, 0.0f, 0.0f};
#pragma unroll 2
  for (int ctile = 0; ctile < CCH / 16; ++ctile) {
    // A fragment: candidate m = lane&15, k-slice = quad*8..+7 (quads 2,3 zero)
    short8 a = (short8){0, 0, 0, 0, 0, 0, 0, 0};
    if (q < 2) a = *(const short8*)(sc + ((ctile * 16 + n) * 16 + q * 8));
#pragma unroll
    for (int i = 0; i < 16; ++i) {
      floatx4 dr = __builtin_amdgcn_mfma_f32_16x16x32_bf16(a, bfr[i], zf, 0, 0, 0);
      // D col = lane&15 (query n); 4 regs + quad partners cover all 16 rows
      mn[i] = fminf(fminf(fminf(dr[0], dr[1]), fminf(dr[2], dr[3])), mn[i]);
    }
  }

#pragma unroll
  for (int i = 0; i < 16; ++i) {
    float m = mn[i];
    m = fminf(m, __shfl_xor(m, 16));
    m = fminf(m, __shfl_xor(m, 32));
    if (lane < 16) {
      unsigned bb = __float_as_uint(m);
      unsigned e = (bb & 0x80000000u) ? ~bb : (bb | 0x80000000u);
      atomicMin(&minarr[qbase + i * 16 + lane], e);
    }
  }
}

__global__ __launch_bounds__(256) void fin_kernel(
    const float4* __restrict__ pts, const unsigned* __restrict__ minarr,
    float* __restrict__ mval) {
  int d = blockIdx.x;
  int t = threadIdx.x;
  float wsum = 0.0f, msum = 0.0f;
#pragma unroll 4
  for (int j = 0; j < 32; ++j) {
    int k = j * 256 + t;
    unsigned u = minarr[(size_t)d * kNP + k];
    unsigned bb = (u & 0x80000000u) ? (u ^ 0x80000000u) : ~u;
    float mnv = __uint_as_float(bb);
    float4 P = pts[(size_t)d * kNP + k];
    if (P.w < 16384.0f) {   // valid query: .w = |p|^2
      wsum += P.w + mnv;
      msum += 1.0f;
    }
  }
#pragma unroll
  for (int off = 32; off; off >>= 1) {
    wsum += __shfl_down(wsum, off);
    msum += __shfl_down(msum, off);
  }
  __shared__ float sw[4], sm[4];
  int wave = t >> 6;
  if ((t & 63) == 0) { sw[wave] = wsum; sm[wave] = msum; }
  __syncthreads();
  if (t == 0) {
    float ws_ = sw[0] + sw[1] + sw[2] + sw[3];
    float ms_ = sm[0] + sm[1] + sm[2] + sm[3];
    mval[d] = ws_ / fmaxf(ms_, 1.0f);
  }
}

__global__ void comb_kernel(const float* __restrict__ mval,
                            float* __restrict__ out) {
  if (threadIdx.x == 0 && blockIdx.x == 0) {
    for (int s = 0; s < kS; ++s) {
      float acc = 0.0f;
      for (int b = 0; b < kB; ++b) {
        int p = b * kS + s;
        float tens = mval[2 * p] + mval[2 * p + 1];
        out[kS + s * kB + b] = tens;
        acc += tens;
      }
      out[s] = acc * (1.0f / kB);
    }
  }
}

extern "C" void kernel_launch(void* const* d_in, const int* in_sizes, int n_in,
                              void* d_out, int out_size, void* d_ws, size_t ws_size,
                              hipStream_t stream) {
  const float* rv = (const float*)d_in[0];
  const float* tgt = (const float*)d_in[1];
  float* ws = (float*)d_ws;
  unsigned short* cf = (unsigned short*)ws;
  float4* pts = (float4*)(ws + OFF_PTS);
  unsigned* minarr = (unsigned*)(ws + OFF_MIN);
  float* mval = ws + OFF_MVAL;
  float* out = (float*)d_out;

  hipLaunchKernelGGL(prep_kernel, dim3(kPairs * kNP / 256), dim3(256), 0, stream,
                     rv, tgt, cf, pts, minarr);
  hipLaunchKernelGGL(nn_kernel, dim3(kDirs * NQB * NCC), dim3(256), 0, stream,
                     cf, pts, minarr);
  hipLaunchKernelGGL(fin_kernel, dim3(kDirs), dim3(256), 0, stream,
                     pts, minarr, mval);
  hipLaunchKernelGGL(comb_kernel, dim3(1), dim3(64), 0, stream, mval, out);
}

// Round 7
// 148.138 us; speedup vs baseline: 1.7691x; 1.7691x over previous
//
#include <hip/hip_runtime.h>
#include <math.h>

constexpr int kH = 64, kW = 128, kB = 2, kS = 4;
constexpr int kNP = kH * kW;          // 8192 points per set
constexpr int kPairs = kB * kS;       // 8
constexpr int kDirs = kPairs * 2;     // 16
constexpr float kPen = 32768.0f;      // exclusion penalty (bf16-exact pow2)
constexpr float kPi = 3.14159265358979323846f;
constexpr float kFovUp = 3.0f * kPi / 180.0f;
constexpr float kFovDown = -25.0f * kPi / 180.0f;

typedef short short8 __attribute__((ext_vector_type(8)));
typedef unsigned short ushort8 __attribute__((ext_vector_type(8)));
typedef float floatx4 __attribute__((ext_vector_type(4)));

// nn tiling: block=256 (4 waves); per wave 8 query tiles of 16 = 128 queries
// -> 512 queries/block. Candidate chunk CCH staged in LDS (32 KB).
constexpr int NCC = 8;                // candidate chunks
constexpr int CCH = kNP / NCC;        // 1024
constexpr int NQB = 16;               // query blocks (8192/512)
// grid = 16 * 16 * 8 = 2048 blocks

// ws layout (float offsets)
// cf   : [kDirs][kNP][16] bf16 -> 1048576 floats @ 0                (4 MB)
// pts  : [kDirs][kNP] float4   -> 524288 @ 1048576                  (2 MB)
// min  : [kDirs][kNP] u32      -> 131072 @ 1572864                  (0.5 MB)
// acc  : [kDirs][2] f32        -> 32 @ 1703936
constexpr size_t OFF_PTS = 1048576;
constexpr size_t OFF_MIN = 1572864;
constexpr size_t OFF_ACC = 1703936;

__device__ __forceinline__ unsigned short f2bf(float v) {
  unsigned u = __float_as_uint(v);
  unsigned r = u + 0x7FFFu + ((u >> 16) & 1u);   // RNE
  return (unsigned short)(r >> 16);
}
__device__ __forceinline__ float bf2f(unsigned short b) {
  return __uint_as_float(((unsigned)b) << 16);
}

// Candidate record, 16 bf16 slots (K-slices: quad0 = k0..7, quad1 = k8..15):
//  k : 0    1    2    3    4    5    6    7  | 8    9    10   11   12-15
//  F : Xh   Xl   Xh   Yh   Yl   Yh   Zh   Zl | Zh   Ch   Cl   Cl2  0
//  G : xh   xh   xl   yh   yh   yl   zh   zh | zl   1    1    1    0
__device__ __forceinline__ void write_rec(unsigned short* dst, float X, float Y,
                                          float Z, float ct) {
  unsigned short Xh = f2bf(X), Yh = f2bf(Y), Zh = f2bf(Z);
  unsigned short Xl = f2bf(X - bf2f(Xh));
  unsigned short Yl = f2bf(Y - bf2f(Yh));
  unsigned short Zl = f2bf(Z - bf2f(Zh));
  unsigned short Ch = f2bf(ct);
  float c1 = ct - bf2f(Ch);
  unsigned short Cl = f2bf(c1);
  unsigned short Cl2 = f2bf(c1 - bf2f(Cl));
  ushort8 lo8 = {Xh, Xl, Xh, Yh, Yl, Yh, Zh, Zl};
  ushort8 hi8 = {Zh, Ch, Cl, Cl2, 0, 0, 0, 0};
  *(ushort8*)dst = lo8;
  *(ushort8*)(dst + 8) = hi8;
}

__global__ __launch_bounds__(256) void prep_kernel(
    const float* __restrict__ rv, const float* __restrict__ tgt,
    unsigned short* __restrict__ cf, float4* __restrict__ pts,
    unsigned* __restrict__ minarr, float* __restrict__ accum) {
  int idx = blockIdx.x * 256 + threadIdx.x;   // [0, kPairs*kNP)
  int p = idx >> 13;
  int k = idx & (kNP - 1);
  int h = k >> 7;
  int w = k & 127;

  float r = rv[idx];
  float pitch = (1.0f - (h + 0.5f) * (1.0f / kH)) * (kFovUp - kFovDown) + kFovDown;
  float yaw = -(((w + 0.5f) * (1.0f / kW)) * 2.0f - 1.0f) * kPi;
  float cp = __cosf(pitch), sp = __sinf(pitch);
  float cy = __cosf(yaw), sy = __sinf(yaw);
  float px = r * cp * cy, py = r * cp * sy, pz = r * sp;
  float mo = (r > 0.0f) ? 1.0f : 0.0f;

  const float* tb = tgt + (size_t)p * 4 * kNP;
  float mt = (tb[k] > 0.0f) ? 1.0f : 0.0f;
  float tx = tb[kNP + k], ty = tb[2 * kNP + k], tz = tb[3 * kNP + k];

  float no = px * px + py * py + pz * pz;
  float nt = tx * tx + ty * ty + tz * tz;
  float co = no + kPen * (1.0f - mo);
  float ct = nt + kPen * (1.0f - mt);

  int d0 = 2 * p, d1 = d0 + 1;
  // pts.w = |p|^2 + pen*(1-m): < 16384 <=> valid query, and equals |p|^2 then.
  pts[(size_t)d0 * kNP + k] = make_float4(px, py, pz, co);
  pts[(size_t)d1 * kNP + k] = make_float4(tx, ty, tz, ct);
  write_rec(cf + ((size_t)d0 * kNP + k) * 16, -2.0f * tx, -2.0f * ty, -2.0f * tz, ct);
  write_rec(cf + ((size_t)d1 * kNP + k) * 16, -2.0f * px, -2.0f * py, -2.0f * pz, co);

  minarr[(size_t)d0 * kNP + k] = 0xFFFFFFFFu;
  minarr[(size_t)d1 * kNP + k] = 0xFFFFFFFFu;
  if (idx < 2 * kDirs) accum[idx] = 0.0f;
}

__global__ __launch_bounds__(256, 4) void nn_kernel(
    const unsigned short* __restrict__ cf, const float4* __restrict__ pts,
    unsigned* __restrict__ minarr) {
  __shared__ unsigned short sc[CCH * 16];   // 32 KB candidate records

  int bid = blockIdx.x;
  int d = bid >> 7;            // / (NQB*NCC) = 128
  int qb = (bid >> 3) & 15;
  int ch = bid & 7;
  int t = threadIdx.x;

  const float4* src = (const float4*)(cf + ((size_t)d * kNP + ch * CCH) * 16);
  float4* dst = (float4*)sc;
#pragma unroll
  for (int i = 0; i < 8; ++i) dst[t + i * 256] = src[t + i * 256];
  __syncthreads();

  int wave = t >> 6, lane = t & 63;
  int n = lane & 15, q = lane >> 4;          // quad = K-slice group (HW-verified)
  int qbase = d * kNP + qb * 512 + wave * 128;

  const short one_bf = (short)0x3F80;        // bf16(1.0)
  short8 bfr[8];
  float mn[8];
#pragma unroll
  for (int i = 0; i < 8; ++i) {
    short8 b = (short8){0, 0, 0, 0, 0, 0, 0, 0};
    if (q < 2) {
      float4 P = pts[qbase + i * 16 + n];
      unsigned short xh = f2bf(P.x), yh = f2bf(P.y), zh = f2bf(P.z);
      unsigned short xl = f2bf(P.x - bf2f(xh));
      unsigned short yl = f2bf(P.y - bf2f(yh));
      unsigned short zl = f2bf(P.z - bf2f(zh));
      if (q == 0)
        b = (short8){(short)xh, (short)xh, (short)xl, (short)yh,
                     (short)yh, (short)yl, (short)zh, (short)zh};
      else
        b = (short8){(short)zl, one_bf, one_bf, one_bf, 0, 0, 0, 0};
    }
    bfr[i] = b;
    mn[i] = 3.0e38f;
  }

  floatx4 zf = {0.0f, 0.0f, 0.0f, 0.0f};
#pragma unroll 2
  for (int ctile = 0; ctile < CCH / 16; ++ctile) {
    // A: candidate m = lane&15, K-slice = quad*8..+7 (quads 2,3 zero).
    short8 a = (short8){0, 0, 0, 0, 0, 0, 0, 0};
    if (q < 2) a = *(const short8*)(sc + ((ctile * 16 + n) * 16 + q * 8));
#pragma unroll
    for (int i = 0; i < 8; ++i) {
      floatx4 dr = __builtin_amdgcn_mfma_f32_16x16x32_bf16(a, bfr[i], zf, 0, 0, 0);
      // fminf chain only: compiler handles MFMA->VALU hazards; inline-asm
      // v_min3 consumers of MFMA results corrupted results (R3/R4/R6).
      mn[i] = fminf(fminf(fminf(dr[0], dr[1]), fminf(dr[2], dr[3])), mn[i]);
    }
  }

#pragma unroll
  for (int i = 0; i < 8; ++i) {
    float m = mn[i];
    m = fminf(m, __shfl_xor(m, 16));
    m = fminf(m, __shfl_xor(m, 32));
    if (lane < 16) {
      unsigned bb = __float_as_uint(m);
      unsigned e = (bb & 0x80000000u) ? ~bb : (bb | 0x80000000u);
      atomicMin(&minarr[qbase + i * 16 + lane], e);
    }
  }
}

__global__ __launch_bounds__(256) void fin_kernel(
    const float4* __restrict__ pts, const unsigned* __restrict__ minarr,
    float* __restrict__ accum) {
  int d = blockIdx.x >> 3;
  int sub = blockIdx.x & 7;
  int t = threadIdx.x;
  float wsum = 0.0f, msum = 0.0f;
#pragma unroll
  for (int j = 0; j < 4; ++j) {
    int k = sub * 1024 + j * 256 + t;
    unsigned u = minarr[(size_t)d * kNP + k];
    unsigned bb = (u & 0x80000000u) ? (u ^ 0x80000000u) : ~u;
    float mnv = __uint_as_float(bb);
    float4 P = pts[(size_t)d * kNP + k];
    if (P.w < 16384.0f) {
      wsum += P.w + mnv;
      msum += 1.0f;
    }
  }
#pragma unroll
  for (int off = 32; off; off >>= 1) {
    wsum += __shfl_down(wsum, off);
    msum += __shfl_down(msum, off);
  }
  __shared__ float sw[4], sm[4];
  int wave = t >> 6;
  if ((t & 63) == 0) { sw[wave] = wsum; sm[wave] = msum; }
  __syncthreads();
  if (t == 0) {
    atomicAdd(&accum[2 * d], sw[0] + sw[1] + sw[2] + sw[3]);
    atomicAdd(&accum[2 * d + 1], sm[0] + sm[1] + sm[2] + sm[3]);
  }
}

__global__ void comb_kernel(const float* __restrict__ accum,
                            float* __restrict__ out) {
  if (threadIdx.x == 0 && blockIdx.x == 0) {
    float mval[kDirs];
    for (int d = 0; d < kDirs; ++d)
      mval[d] = accum[2 * d] / fmaxf(accum[2 * d + 1], 1.0f);
    for (int s = 0; s < kS; ++s) {
      float acc = 0.0f;
      for (int b = 0; b < kB; ++b) {
        int p = b * kS + s;
        float tens = mval[2 * p] + mval[2 * p + 1];
        out[kS + s * kB + b] = tens;
        acc += tens;
      }
      out[s] = acc * (1.0f / kB);
    }
  }
}

extern "C" void kernel_launch(void* const* d_in, const int* in_sizes, int n_in,
                              void* d_out, int out_size, void* d_ws, size_t ws_size,
                              hipStream_t stream) {
  const float* rv = (const float*)d_in[0];
  const float* tgt = (const float*)d_in[1];
  float* ws = (float*)d_ws;
  unsigned short* cf = (unsigned short*)ws;
  float4* pts = (float4*)(ws + OFF_PTS);
  unsigned* minarr = (unsigned*)(ws + OFF_MIN);
  float* accum = ws + OFF_ACC;
  float* out = (float*)d_out;

  hipLaunchKernelGGL(prep_kernel, dim3(kPairs * kNP / 256), dim3(256), 0, stream,
                     rv, tgt, cf, pts, minarr, accum);
  hipLaunchKernelGGL(nn_kernel, dim3(kDirs * NQB * NCC), dim3(256), 0, stream,
                     cf, pts, minarr);
  hipLaunchKernelGGL(fin_kernel, dim3(kDirs * 8), dim3(256), 0, stream,
                     pts, minarr, accum);
  hipLaunchKernelGGL(comb_kernel, dim3(1), dim3(64), 0, stream, accum, out);
}